// Round 1
// baseline (214.196 us; speedup 1.0000x reference)
//
#include <hip/hip_runtime.h>

// MFMA fragment types (f16)
typedef _Float16 f16x8 __attribute__((ext_vector_type(8)));
typedef __fp16   fp16x2 __attribute__((ext_vector_type(2)));
typedef float f32x16 __attribute__((ext_vector_type(16)));

__device__ __forceinline__ unsigned pkrtz(float a, float b) {
    fp16x2 h = __builtin_amdgcn_cvt_pkrtz(a, b);   // src0->low, src1->high
    union { fp16x2 h; unsigned u; } c; c.h = h; return c.u;
}

__device__ __forceinline__ unsigned short f2h(float f) {
    _Float16 h = (_Float16)f;
    union { _Float16 h; unsigned short s; } c; c.h = h; return c.s;
}

// ---------------------------------------------------------------------------
// prep (height stage): per (b, bx=w) block: slab[k=h][c],
//   Q -> Qg [b][4096][64] f16 row-major ; V -> Vtg [b][64][4096] f16 (T)
// r0 change: weights read via SCALAR loads (readfirstlane'd jg makes the
// address wave-uniform -> s_load on scalar pipe). Removes 32KB LDS staging
// and the 8x ds_read_b128/iter that made this loop LDS-issue-bound at
// 1 wave/SIMD. Loop floor is now the 2048 v_fmac per thread.
// ---------------------------------------------------------------------------
__global__ __launch_bounds__(256) void prep_kernel(
    const float* __restrict__ src,
    const float* __restrict__ wq, const float* __restrict__ bq,
    const float* __restrict__ wv, const float* __restrict__ bv,
    unsigned short* __restrict__ Qg, unsigned short* __restrict__ Vtg)
{
    __shared__ float slab[64][65];

    const int t  = threadIdx.x;
    const int bx = blockIdx.x, b = blockIdx.y;

    {   // stage slab: k=h rows (stride 4096), bx=w fixed
        const int k = t >> 2, c0 = (t & 3) << 4;
        const size_t sb = (size_t)b*262144 + (size_t)k*4096 + (size_t)bx*64 + c0;
        #pragma unroll
        for (int i = 0; i < 4; ++i)
            *(float4*)&slab[k][c0 + i*4] = *(const float4*)&src[sb + i*4];
    }
    __syncthreads();

    const int c = t & 63;
    const int jg = __builtin_amdgcn_readfirstlane(t >> 6);   // wave-uniform
    const float* __restrict__ wqr = wq + jg*16;
    const float* __restrict__ wvr = wv + jg*16;
    float qa[16], va[16];
    #pragma unroll
    for (int jj = 0; jj < 16; ++jj) { qa[jj] = bq[jg*16+jj]; va[jj] = bv[jg*16+jj]; }
    #pragma unroll 4
    for (int k = 0; k < 64; ++k) {
        const float xv = slab[k][c];
        #pragma unroll
        for (int jj = 0; jj < 16; ++jj) {
            qa[jj] += xv * wqr[k*64 + jj];
            va[jj] += xv * wvr[k*64 + jj];
        }
    }
    const int token = bx*64 + c;
    union { unsigned u[8]; uint4 v[2]; } qp;
    #pragma unroll
    for (int jj = 0; jj < 8; ++jj) qp.u[jj] = pkrtz(qa[2*jj], qa[2*jj+1]);
    const size_t qoff = ((size_t)b*4096 + token)*64 + jg*16;
    *(uint4*)&Qg[qoff]     = qp.v[0];
    *(uint4*)&Qg[qoff + 8] = qp.v[1];
    #pragma unroll
    for (int jj = 0; jj < 16; ++jj)
        Vtg[((size_t)b*64 + jg*16 + jj)*4096 + token] = f2h(va[jj]);
}

// ---------------------------------------------------------------------------
// prep_w (width stage) FUSED with fold_h:
//   x1 = feature + g*sum_ks(P_h) computed during slab staging, then Q/V GEMM.
// Same scalar-weight treatment as prep_kernel.
// ---------------------------------------------------------------------------
__global__ __launch_bounds__(256) void prep_w_kernel(
    const float* __restrict__ feature, const float* __restrict__ Pin,
    const float* __restrict__ gate,
    const float* __restrict__ wq, const float* __restrict__ bq,
    const float* __restrict__ wv, const float* __restrict__ bv,
    unsigned short* __restrict__ Qg, unsigned short* __restrict__ Vtg,
    float* __restrict__ x1out, int nsplit)
{
    __shared__ float slab[64][65];

    const int t  = threadIdx.x;
    const int bx = blockIdx.x, b = blockIdx.y;   // bx = h

    {   // stage slab with inline fold: P_h[ks][b][d=h][token=w*64+c]
        const int k = t >> 2, c0 = (t & 3) << 4;
        const size_t off = (size_t)bx*4096 + (size_t)k*64 + c0;  // h*4096 + w*64 + c
        const size_t fb  = (size_t)b*262144 + off;
        const float g = gate[0];
        #pragma unroll
        for (int i = 0; i < 4; ++i) {
            float4 v  = *(const float4*)&feature[fb + i*4];
            float sx = 0.f, sy = 0.f, sz = 0.f, sw = 0.f;
            for (int ks = 0; ks < nsplit; ++ks) {
                float4 pk = *(const float4*)&Pin[((size_t)(ks*4 + b) << 18) + off + i*4];
                sx += pk.x; sy += pk.y; sz += pk.z; sw += pk.w;
            }
            v.x += g * sx; v.y += g * sy; v.z += g * sz; v.w += g * sw;
            *(float4*)&slab[k][c0 + i*4] = v;
            *(float4*)&x1out[fb + i*4] = v;
        }
    }
    __syncthreads();

    const int c = t & 63;
    const int jg = __builtin_amdgcn_readfirstlane(t >> 6);   // wave-uniform
    const float* __restrict__ wqr = wq + jg*16;
    const float* __restrict__ wvr = wv + jg*16;
    float qa[16], va[16];
    #pragma unroll
    for (int jj = 0; jj < 16; ++jj) { qa[jj] = bq[jg*16+jj]; va[jj] = bv[jg*16+jj]; }
    #pragma unroll 4
    for (int k = 0; k < 64; ++k) {
        const float xv = slab[k][c];
        #pragma unroll
        for (int jj = 0; jj < 16; ++jj) {
            qa[jj] += xv * wqr[k*64 + jj];
            va[jj] += xv * wvr[k*64 + jj];
        }
    }
    const int token = bx*64 + c;
    union { unsigned u[8]; uint4 v[2]; } qp;
    #pragma unroll
    for (int jj = 0; jj < 8; ++jj) qp.u[jj] = pkrtz(qa[2*jj], qa[2*jj+1]);
    const size_t qoff = ((size_t)b*4096 + token)*64 + jg*16;
    *(uint4*)&Qg[qoff]     = qp.v[0];
    *(uint4*)&Qg[qoff + 8] = qp.v[1];
    #pragma unroll
    for (int jj = 0; jj < 16; ++jj)
        Vtg[((size_t)b*64 + jg*16 + jj)*4096 + token] = f2h(va[jj]);
}

// ---------------------------------------------------------------------------
// attn v15 = v14 + occupancy (ksplit 4->8 from launcher: grid 1024 blocks =
// 4 blocks/CU; LDS 36.9KB*4 = 147KB fits 160KB) + hoisted zero C-operand
// (fz lives across the loop -> no 32x v_mov tt-init per tile).
// f16 32x32x16 MFMA, no cross-lane S moves; V staged with per-16 key
// permutation nu so the S·V A-frag for step sp is exactly C-regs
// [8sp..8sp+7] of T = K·Q^T. Sigmoid pairwise: ONE rcp per 2 scores;
// t clamped <= 60 so d0*d1 can't reach inf. LDS ping-pong, 1 barrier/iter.
// ---------------------------------------------------------------------------
__global__ __launch_bounds__(256) void attn_kernel(
    const unsigned short* __restrict__ Qg,
    const unsigned short* __restrict__ Vtg,
    float* __restrict__ P)
{
    __shared__ unsigned short Ksh[2][64][72];
    __shared__ unsigned short Vts[2][64][72];

    const int t = threadIdx.x;
    const int mb = blockIdx.x, b = blockIdx.y, ksplit = blockIdx.z;
    const int nsp = gridDim.z;
    const int niter = 64 / nsp;
    const int keybase = ksplit * (4096 / nsp);
    const int lane = t & 63, w = t >> 6;
    const int l32 = lane & 31, hi = lane >> 5;

    const unsigned short* Qbase = Qg  + (size_t)b*262144;
    const unsigned short* Vbase = Vtg + (size_t)b*262144;

    // Q B-frags (n=query=l32, k=d=s*16+hi*8+j), scaled by -0.125*log2(e)
    f16x8 qb[4];
    {
        const unsigned short* qrow = Qbase + (size_t)(mb*128 + w*32 + l32)*64 + hi*8;
        const _Float16 sc = (_Float16)(-0.180336880f);
        #pragma unroll
        for (int s = 0; s < 4; ++s) {
            f16x8 q = *(const f16x8*)(qrow + s*16);
            qb[s] = q * sc;
        }
    }

    f32x16 fz;
    #pragma unroll
    for (int i = 0; i < 16; ++i) fz[i] = 0.f;

    f32x16 y[2];
    y[0] = fz; y[1] = fz;

    const int lrow = t >> 2;
    const int loff = (t & 3) << 4;   // 16-key block per staging quarter
    {   // prologue: stage tile 0 into buffer 0 (V with nu swizzle)
        const uint4* gk = (const uint4*)(Qbase + (size_t)(keybase + lrow)*64 + loff);
        uint4 k0 = gk[0], k1 = gk[1];
        const uint4* gv = (const uint4*)(Vbase + (size_t)lrow*4096 + keybase + loff);
        uint4 v0 = gv[0], v1 = gv[1];
        *(uint4*)&Ksh[0][lrow][loff]     = k0;
        *(uint4*)&Ksh[0][lrow][loff + 8] = k1;
        uint4 pa = { v0.x, v0.y, v1.x, v1.y };   // slots 0-7 = keys 0-3,8-11
        uint4 pb = { v0.z, v0.w, v1.z, v1.w };   // slots 8-15 = keys 4-7,12-15
        *(uint4*)&Vts[0][lrow][loff]     = pa;
        *(uint4*)&Vts[0][lrow][loff + 8] = pb;
    }
    __syncthreads();

    for (int kb = 0; kb < niter; ++kb) {
        const int cur = kb & 1, nxt = cur ^ 1;

        // prefetch next tile into registers (in flight across compute phase)
        uint4 nk0 = {0,0,0,0}, nk1 = {0,0,0,0}, nv0 = {0,0,0,0}, nv1 = {0,0,0,0};
        if (kb < niter - 1) {
            const int keyn = keybase + (kb + 1)*64;
            const uint4* gk = (const uint4*)(Qbase + (size_t)(keyn + lrow)*64 + loff);
            nk0 = gk[0]; nk1 = gk[1];
            const uint4* gv = (const uint4*)(Vbase + (size_t)lrow*4096 + keyn + loff);
            nv0 = gv[0]; nv1 = gv[1];
        }

        // T = K·Qs^T : tt[u] covers keys u*32..+32 (scale pre-folded)
        f32x16 tt[2];
        #pragma unroll
        for (int s = 0; s < 4; ++s) {
            const int co = s*16 + hi*8;
            f16x8 ka0 = *(const f16x8*)&Ksh[cur][l32][co];
            f16x8 ka1 = *(const f16x8*)&Ksh[cur][32 + l32][co];
            if (s == 0) {
                tt[0] = __builtin_amdgcn_mfma_f32_32x32x16_f16(ka0, qb[0], fz, 0,0,0);
                tt[1] = __builtin_amdgcn_mfma_f32_32x32x16_f16(ka1, qb[0], fz, 0,0,0);
            } else {
                tt[0] = __builtin_amdgcn_mfma_f32_32x32x16_f16(ka0, qb[s], tt[0], 0,0,0);
                tt[1] = __builtin_amdgcn_mfma_f32_32x32x16_f16(ka1, qb[s], tt[1], 0,0,0);
            }
        }

        // sigmoid (pairwise rcp, t clamped) -> pack -> DIRECT A-frag
        #pragma unroll
        for (int u = 0; u < 2; ++u) {
            unsigned pk_[8];
            #pragma unroll
            for (int pr = 0; pr < 8; ++pr) {
                float t0 = __builtin_fminf(tt[u][2*pr+0], 60.0f);
                float t1 = __builtin_fminf(tt[u][2*pr+1], 60.0f);
                float e0 = __builtin_exp2f(t0);
                float e1 = __builtin_exp2f(t1);
                float d0 = 1.0f + e0, d1 = 1.0f + e1;
                float rr = __builtin_amdgcn_rcpf(d0 * d1);
                pk_[pr] = pkrtz(rr * d1, rr * d0);
            }
            #pragma unroll
            for (int sp = 0; sp < 2; ++sp) {
                union { unsigned u4[4]; f16x8 v; } sa;
                sa.u4[0] = pk_[sp*4 + 0];
                sa.u4[1] = pk_[sp*4 + 1];
                sa.u4[2] = pk_[sp*4 + 2];
                sa.u4[3] = pk_[sp*4 + 3];
                const int ks = u*2 + sp;
                const int co = ks*16 + hi*8;
                f16x8 vb0 = *(const f16x8*)&Vts[cur][l32][co];
                f16x8 vb1 = *(const f16x8*)&Vts[cur][32 + l32][co];
                y[0] = __builtin_amdgcn_mfma_f32_32x32x16_f16(sa.v, vb0, y[0], 0,0,0);
                y[1] = __builtin_amdgcn_mfma_f32_32x32x16_f16(sa.v, vb1, y[1], 0,0,0);
            }
        }

        // drain prefetch into the idle buffer (nobody reads nxt this iter)
        if (kb < niter - 1) {
            *(uint4*)&Ksh[nxt][lrow][loff]     = nk0;
            *(uint4*)&Ksh[nxt][lrow][loff + 8] = nk1;
            uint4 pa = { nv0.x, nv0.y, nv1.x, nv1.y };
            uint4 pb = { nv0.z, nv0.w, nv1.z, nv1.w };
            *(uint4*)&Vts[nxt][lrow][loff]     = pa;
            *(uint4*)&Vts[nxt][lrow][loff + 8] = pb;
        }
        __syncthreads();   // single barrier per iteration
    }

    // epilogue: P[ksplit][b][d][token]; token = mb*128 + w*32 + 8g + 4hi + e
    float* Pp = P + (((size_t)(ksplit*4 + b)) << 18);
    const int token0 = mb*128 + w*32 + hi*4;
    #pragma unroll
    for (int dt = 0; dt < 2; ++dt) {
        const int d = dt*32 + l32;
        #pragma unroll
        for (int g = 0; g < 4; ++g) {
            float4 v;
            v.x = y[dt][4*g+0]; v.y = y[dt][4*g+1];
            v.z = y[dt][4*g+2]; v.w = y[dt][4*g+3];
            *(float4*)&Pp[(size_t)d*4096 + token0 + 8*g] = v;
        }
    }
}

// ---------------------------------------------------------------------------
// final: out = p * (feature + x1 + g*sum_ks P_w[ks][b][d=w][token=h*64+c])
// ---------------------------------------------------------------------------
__global__ __launch_bounds__(256) void final_kernel(
    const float* __restrict__ feature, const float* __restrict__ x1,
    const float* __restrict__ Pin, const float* __restrict__ predict,
    const float* __restrict__ conv_w, const float* __restrict__ conv_b,
    const float* __restrict__ gate, float* __restrict__ out, int nsplit)
{
    const int i4 = blockIdx.x * 256 + threadIdx.x;   // [0, 262144)
    const int j = i4 << 2;
    const int pix = j >> 6;
    const float* row = predict + (size_t)pix * 19;
    float pv = conv_b[0];
    #pragma unroll
    for (int i = 0; i < 19; ++i) {
        float sg = __builtin_amdgcn_rcpf(1.0f + __builtin_exp2f(-1.442695041f * row[i]));
        pv += (1.0f - sg) * conv_w[i];
    }

    const int b = j >> 18, h = (j >> 12) & 63, d = (j >> 6) & 63, c = j & 63;
    const size_t pif = ((size_t)(b*64 + d) << 12) + h*64 + c;
    float sx = 0.f, sy = 0.f, sz = 0.f, sw = 0.f;
    for (int ks = 0; ks < nsplit; ++ks) {
        float4 pk = *(const float4*)&Pin[((size_t)ks << 20) + pif];
        sx += pk.x; sy += pk.y; sz += pk.z; sw += pk.w;
    }
    const float g = gate[0];
    float4 f = ((const float4*)feature)[i4];
    float4 x = ((const float4*)x1)[i4];
    float4 o;
    o.x = pv * (f.x + x.x + g * sx);
    o.y = pv * (f.y + x.y + g * sy);
    o.z = pv * (f.z + x.z + g * sz);
    o.w = pv * (f.w + x.w + g * sw);
    ((float4*)out)[i4] = o;
}

extern "C" void kernel_launch(void* const* d_in, const int* in_sizes, int n_in,
                              void* d_out, int out_size, void* d_ws, size_t ws_size,
                              hipStream_t stream) {
    const float* feature = (const float*)d_in[0];
    const float* predict = (const float*)d_in[1];
    const float* hq_w = (const float*)d_in[2];
    const float* hq_b = (const float*)d_in[3];
    const float* hv_w = (const float*)d_in[4];
    const float* hv_b = (const float*)d_in[5];
    const float* wq_w = (const float*)d_in[6];
    const float* wq_b = (const float*)d_in[7];
    const float* wv_w = (const float*)d_in[8];
    const float* wv_b = (const float*)d_in[9];
    const float* h_gate = (const float*)d_in[10];
    const float* w_gate = (const float*)d_in[11];
    const float* conv_w = (const float*)d_in[12];
    const float* conv_b = (const float*)d_in[13];
    float* out = (float*)d_out;

    // workspace: Qg 2MB | Vtg 2MB | x1 4MB | P nsplit*4MB
    // nsplit=8 -> 40 MiB (grid 1024 blocks = 4 blocks/CU); fallback 4 if ws small
    char* ws = (char*)d_ws;
    unsigned short* Qg  = (unsigned short*)(ws);
    unsigned short* Vtg = (unsigned short*)(ws + (2u << 20));
    float*          x1  = (float*)(ws + (4u << 20));
    float*          P   = (float*)(ws + (8u << 20));
    const int nsplit = (ws_size >= ((size_t)40 << 20)) ? 8 : 4;

    dim3 blk(256);
    // height stage
    prep_kernel<<<dim3(64, 4), blk, 0, stream>>>(feature, hq_w, hq_b, hv_w, hv_b,
                                                 Qg, Vtg);
    attn_kernel<<<dim3(32, 4, nsplit), blk, 0, stream>>>(Qg, Vtg, P);
    // width stage: x1 = feature + h_gate*sum(P) fused into staging
    prep_w_kernel<<<dim3(64, 4), blk, 0, stream>>>(feature, P, h_gate,
                                                   wq_w, wq_b, wv_w, wv_b,
                                                   Qg, Vtg, x1, nsplit);
    attn_kernel<<<dim3(32, 4, nsplit), blk, 0, stream>>>(Qg, Vtg, P);
    // out = p * (feature + x1 + w_gate*sum(P))
    final_kernel<<<dim3(1024), blk, 0, stream>>>(feature, x1, P, predict,
                                                 conv_w, conv_b, w_gate, out, nsplit);
}

// Round 2
// 190.927 us; speedup vs baseline: 1.1219x; 1.1219x over previous
//
#include <hip/hip_runtime.h>

// MFMA fragment types (f16)
typedef _Float16 f16x8 __attribute__((ext_vector_type(8)));
typedef __fp16   fp16x2 __attribute__((ext_vector_type(2)));
typedef float f32x16 __attribute__((ext_vector_type(16)));

__device__ __forceinline__ unsigned pkrtz(float a, float b) {
    fp16x2 h = __builtin_amdgcn_cvt_pkrtz(a, b);   // src0->low, src1->high
    union { fp16x2 h; unsigned u; } c; c.h = h; return c.u;
}

__device__ __forceinline__ unsigned short f2h(float f) {
    _Float16 h = (_Float16)f;
    union { _Float16 h; unsigned short s; } c; c.h = h; return c.s;
}

// ---------------------------------------------------------------------------
// prep (height stage, r0-proven): per (b, bx=w) block: slab[k=h][c],
//   Q -> Qg [b][4096][64] f16 row-major ; V -> Vtg [b][64][4096] f16 (T)
// (r1's scalar-weight variant regressed; reverted to LDS-staged weights.)
// ---------------------------------------------------------------------------
__global__ __launch_bounds__(256) void prep_kernel(
    const float* __restrict__ src,
    const float* __restrict__ wq, const float* __restrict__ bq,
    const float* __restrict__ wv, const float* __restrict__ bv,
    unsigned short* __restrict__ Qg, unsigned short* __restrict__ Vtg)
{
    __shared__ float slab[64][65];
    __shared__ float wqs[4096];
    __shared__ float wvs[4096];

    const int t  = threadIdx.x;
    const int bx = blockIdx.x, b = blockIdx.y;

    {   // stage weights
        const float4* wq4 = (const float4*)wq;
        const float4* wv4 = (const float4*)wv;
        float4* q4 = (float4*)wqs; float4* v4 = (float4*)wvs;
        #pragma unroll
        for (int i = 0; i < 4; ++i) {
            q4[i*256 + t] = wq4[i*256 + t];
            v4[i*256 + t] = wv4[i*256 + t];
        }
    }
    {   // stage slab: k=h rows (stride 4096), bx=w fixed
        const int k = t >> 2, c0 = (t & 3) << 4;
        const size_t sb = (size_t)b*262144 + (size_t)k*4096 + (size_t)bx*64 + c0;
        #pragma unroll
        for (int i = 0; i < 4; ++i)
            *(float4*)&slab[k][c0 + i*4] = *(const float4*)&src[sb + i*4];
    }
    __syncthreads();

    const int c = t & 63, jg = t >> 6;
    float qa[16], va[16];
    #pragma unroll
    for (int jj = 0; jj < 16; ++jj) { qa[jj] = bq[jg*16+jj]; va[jj] = bv[jg*16+jj]; }
    for (int k = 0; k < 64; ++k) {
        const float xv = slab[k][c];
        const float* wqr = &wqs[k*64 + jg*16];
        const float* wvr = &wvs[k*64 + jg*16];
        #pragma unroll
        for (int jj = 0; jj < 16; ++jj) {
            qa[jj] += xv * wqr[jj];
            va[jj] += xv * wvr[jj];
        }
    }
    const int token = bx*64 + c;
    union { unsigned u[8]; uint4 v[2]; } qp;
    #pragma unroll
    for (int jj = 0; jj < 8; ++jj) qp.u[jj] = pkrtz(qa[2*jj], qa[2*jj+1]);
    const size_t qoff = ((size_t)b*4096 + token)*64 + jg*16;
    *(uint4*)&Qg[qoff]     = qp.v[0];
    *(uint4*)&Qg[qoff + 8] = qp.v[1];
    #pragma unroll
    for (int jj = 0; jj < 16; ++jj)
        Vtg[((size_t)b*64 + jg*16 + jj)*4096 + token] = f2h(va[jj]);
}

// ---------------------------------------------------------------------------
// prep_w (width stage, r0-proven) FUSED with fold_h:
//   x1 = feature + g*sum_ks(P_h) computed during slab staging, then Q/V GEMM.
// ---------------------------------------------------------------------------
__global__ __launch_bounds__(256) void prep_w_kernel(
    const float* __restrict__ feature, const float* __restrict__ Pin,
    const float* __restrict__ gate,
    const float* __restrict__ wq, const float* __restrict__ bq,
    const float* __restrict__ wv, const float* __restrict__ bv,
    unsigned short* __restrict__ Qg, unsigned short* __restrict__ Vtg,
    float* __restrict__ x1out, int nsplit)
{
    __shared__ float slab[64][65];
    __shared__ float wqs[4096];
    __shared__ float wvs[4096];

    const int t  = threadIdx.x;
    const int bx = blockIdx.x, b = blockIdx.y;   // bx = h

    {   // stage weights
        const float4* wq4 = (const float4*)wq;
        const float4* wv4 = (const float4*)wv;
        float4* q4 = (float4*)wqs; float4* v4 = (float4*)wvs;
        #pragma unroll
        for (int i = 0; i < 4; ++i) {
            q4[i*256 + t] = wq4[i*256 + t];
            v4[i*256 + t] = wv4[i*256 + t];
        }
    }
    {   // stage slab with inline fold: P_h[ks][b][d=h][token=w*64+c]
        const int k = t >> 2, c0 = (t & 3) << 4;
        const size_t off = (size_t)bx*4096 + (size_t)k*64 + c0;  // h*4096 + w*64 + c
        const size_t fb  = (size_t)b*262144 + off;
        const float g = gate[0];
        #pragma unroll
        for (int i = 0; i < 4; ++i) {
            float4 v  = *(const float4*)&feature[fb + i*4];
            float sx = 0.f, sy = 0.f, sz = 0.f, sw = 0.f;
            for (int ks = 0; ks < nsplit; ++ks) {
                float4 pk = *(const float4*)&Pin[((size_t)(ks*4 + b) << 18) + off + i*4];
                sx += pk.x; sy += pk.y; sz += pk.z; sw += pk.w;
            }
            v.x += g * sx; v.y += g * sy; v.z += g * sz; v.w += g * sw;
            *(float4*)&slab[k][c0 + i*4] = v;
            *(float4*)&x1out[fb + i*4] = v;
        }
    }
    __syncthreads();

    const int c = t & 63, jg = t >> 6;
    float qa[16], va[16];
    #pragma unroll
    for (int jj = 0; jj < 16; ++jj) { qa[jj] = bq[jg*16+jj]; va[jj] = bv[jg*16+jj]; }
    for (int k = 0; k < 64; ++k) {
        const float xv = slab[k][c];
        const float* wqr = &wqs[k*64 + jg*16];
        const float* wvr = &wvs[k*64 + jg*16];
        #pragma unroll
        for (int jj = 0; jj < 16; ++jj) {
            qa[jj] += xv * wqr[jj];
            va[jj] += xv * wvr[jj];
        }
    }
    const int token = bx*64 + c;
    union { unsigned u[8]; uint4 v[2]; } qp;
    #pragma unroll
    for (int jj = 0; jj < 8; ++jj) qp.u[jj] = pkrtz(qa[2*jj], qa[2*jj+1]);
    const size_t qoff = ((size_t)b*4096 + token)*64 + jg*16;
    *(uint4*)&Qg[qoff]     = qp.v[0];
    *(uint4*)&Qg[qoff + 8] = qp.v[1];
    #pragma unroll
    for (int jj = 0; jj < 16; ++jj)
        Vtg[((size_t)b*64 + jg*16 + jj)*4096 + token] = f2h(va[jj]);
}

// ---------------------------------------------------------------------------
// attn v16 = v14 with SINGLE-buffered LDS (18.4 KB, was 36.9 KB double-buf).
// Theory: residency was capped at ~1 block/CU by LDS footprint; the kernel is
// latency-bound (no pipe >30% busy at 44.8us), so halving LDS to get 2-3
// co-resident blocks/CU is the lever. Cost: 2 barriers/iter instead of 1;
// register prefetch still spans the compute phase. s_setprio(1) wraps compute
// (pays when co-resident blocks sit at different phases; m191).
// Math unchanged from v14: f16 32x32x16 MFMA, V nu-permuted so S-V A-frag ==
// C-regs of T=K*Q^T; pairwise-rcp sigmoid, t clamped <= 60.
// ---------------------------------------------------------------------------
__global__ __launch_bounds__(256) void attn_kernel(
    const unsigned short* __restrict__ Qg,
    const unsigned short* __restrict__ Vtg,
    float* __restrict__ P)
{
    __shared__ unsigned short Ksh[64][72];
    __shared__ unsigned short Vts[64][72];

    const int t = threadIdx.x;
    const int mb = blockIdx.x, b = blockIdx.y, ksplit = blockIdx.z;
    const int nsp = gridDim.z;
    const int niter = 64 / nsp;
    const int keybase = ksplit * (4096 / nsp);
    const int lane = t & 63, w = t >> 6;
    const int l32 = lane & 31, hi = lane >> 5;

    const unsigned short* Qbase = Qg  + (size_t)b*262144;
    const unsigned short* Vbase = Vtg + (size_t)b*262144;

    // Q B-frags (n=query=l32, k=d=s*16+hi*8+j), scaled by -0.125*log2(e)
    f16x8 qb[4];
    {
        const unsigned short* qrow = Qbase + (size_t)(mb*128 + w*32 + l32)*64 + hi*8;
        const _Float16 sc = (_Float16)(-0.180336880f);
        #pragma unroll
        for (int s = 0; s < 4; ++s) {
            f16x8 q = *(const f16x8*)(qrow + s*16);
            qb[s] = q * sc;
        }
    }

    f32x16 fz;
    #pragma unroll
    for (int i = 0; i < 16; ++i) fz[i] = 0.f;

    f32x16 y[2];
    y[0] = fz; y[1] = fz;

    const int lrow = t >> 2;
    const int loff = (t & 3) << 4;   // 16-key block per staging quarter
    {   // prologue: stage tile 0 (V with nu swizzle)
        const uint4* gk = (const uint4*)(Qbase + (size_t)(keybase + lrow)*64 + loff);
        uint4 k0 = gk[0], k1 = gk[1];
        const uint4* gv = (const uint4*)(Vbase + (size_t)lrow*4096 + keybase + loff);
        uint4 v0 = gv[0], v1 = gv[1];
        *(uint4*)&Ksh[lrow][loff]     = k0;
        *(uint4*)&Ksh[lrow][loff + 8] = k1;
        uint4 pa = { v0.x, v0.y, v1.x, v1.y };   // slots 0-7 = keys 0-3,8-11
        uint4 pb = { v0.z, v0.w, v1.z, v1.w };   // slots 8-15 = keys 4-7,12-15
        *(uint4*)&Vts[lrow][loff]     = pa;
        *(uint4*)&Vts[lrow][loff + 8] = pb;
    }
    __syncthreads();

    for (int kb = 0; kb < niter; ++kb) {
        // prefetch next tile into registers (in flight across compute phase)
        uint4 nk0 = {0,0,0,0}, nk1 = {0,0,0,0}, nv0 = {0,0,0,0}, nv1 = {0,0,0,0};
        if (kb < niter - 1) {
            const int keyn = keybase + (kb + 1)*64;
            const uint4* gk = (const uint4*)(Qbase + (size_t)(keyn + lrow)*64 + loff);
            nk0 = gk[0]; nk1 = gk[1];
            const uint4* gv = (const uint4*)(Vbase + (size_t)lrow*4096 + keyn + loff);
            nv0 = gv[0]; nv1 = gv[1];
        }

        __builtin_amdgcn_s_setprio(1);

        // T = K·Qs^T : tt[u] covers keys u*32..+32 (scale pre-folded)
        f32x16 tt[2];
        #pragma unroll
        for (int s = 0; s < 4; ++s) {
            const int co = s*16 + hi*8;
            f16x8 ka0 = *(const f16x8*)&Ksh[l32][co];
            f16x8 ka1 = *(const f16x8*)&Ksh[32 + l32][co];
            if (s == 0) {
                tt[0] = __builtin_amdgcn_mfma_f32_32x32x16_f16(ka0, qb[0], fz, 0,0,0);
                tt[1] = __builtin_amdgcn_mfma_f32_32x32x16_f16(ka1, qb[0], fz, 0,0,0);
            } else {
                tt[0] = __builtin_amdgcn_mfma_f32_32x32x16_f16(ka0, qb[s], tt[0], 0,0,0);
                tt[1] = __builtin_amdgcn_mfma_f32_32x32x16_f16(ka1, qb[s], tt[1], 0,0,0);
            }
        }

        // sigmoid (pairwise rcp, t clamped) -> pack -> DIRECT A-frag
        #pragma unroll
        for (int u = 0; u < 2; ++u) {
            unsigned pk_[8];
            #pragma unroll
            for (int pr = 0; pr < 8; ++pr) {
                float t0 = __builtin_fminf(tt[u][2*pr+0], 60.0f);
                float t1 = __builtin_fminf(tt[u][2*pr+1], 60.0f);
                float e0 = __builtin_exp2f(t0);
                float e1 = __builtin_exp2f(t1);
                float d0 = 1.0f + e0, d1 = 1.0f + e1;
                float rr = __builtin_amdgcn_rcpf(d0 * d1);
                pk_[pr] = pkrtz(rr * d1, rr * d0);
            }
            #pragma unroll
            for (int sp = 0; sp < 2; ++sp) {
                union { unsigned u4[4]; f16x8 v; } sa;
                sa.u4[0] = pk_[sp*4 + 0];
                sa.u4[1] = pk_[sp*4 + 1];
                sa.u4[2] = pk_[sp*4 + 2];
                sa.u4[3] = pk_[sp*4 + 3];
                const int ks = u*2 + sp;
                const int co = ks*16 + hi*8;
                f16x8 vb0 = *(const f16x8*)&Vts[l32][co];
                f16x8 vb1 = *(const f16x8*)&Vts[32 + l32][co];
                y[0] = __builtin_amdgcn_mfma_f32_32x32x16_f16(sa.v, vb0, y[0], 0,0,0);
                y[1] = __builtin_amdgcn_mfma_f32_32x32x16_f16(sa.v, vb1, y[1], 0,0,0);
            }
        }

        __builtin_amdgcn_s_setprio(0);

        if (kb < niter - 1) {
            __syncthreads();   // A: all waves done READING this tile
            *(uint4*)&Ksh[lrow][loff]     = nk0;
            *(uint4*)&Ksh[lrow][loff + 8] = nk1;
            uint4 pa = { nv0.x, nv0.y, nv1.x, nv1.y };
            uint4 pb = { nv0.z, nv0.w, nv1.z, nv1.w };
            *(uint4*)&Vts[lrow][loff]     = pa;
            *(uint4*)&Vts[lrow][loff + 8] = pb;
            __syncthreads();   // B: writes visible before next compute
        }
    }

    // epilogue: P[ksplit][b][d][token]; token = mb*128 + w*32 + 8g + 4hi + e
    float* Pp = P + (((size_t)(ksplit*4 + b)) << 18);
    const int token0 = mb*128 + w*32 + hi*4;
    #pragma unroll
    for (int dt = 0; dt < 2; ++dt) {
        const int d = dt*32 + l32;
        #pragma unroll
        for (int g = 0; g < 4; ++g) {
            float4 v;
            v.x = y[dt][4*g+0]; v.y = y[dt][4*g+1];
            v.z = y[dt][4*g+2]; v.w = y[dt][4*g+3];
            *(float4*)&Pp[(size_t)d*4096 + token0 + 8*g] = v;
        }
    }
}

// ---------------------------------------------------------------------------
// final: out = p * (feature + x1 + g*sum_ks P_w[ks][b][d=w][token=h*64+c])
// ---------------------------------------------------------------------------
__global__ __launch_bounds__(256) void final_kernel(
    const float* __restrict__ feature, const float* __restrict__ x1,
    const float* __restrict__ Pin, const float* __restrict__ predict,
    const float* __restrict__ conv_w, const float* __restrict__ conv_b,
    const float* __restrict__ gate, float* __restrict__ out, int nsplit)
{
    const int i4 = blockIdx.x * 256 + threadIdx.x;   // [0, 262144)
    const int j = i4 << 2;
    const int pix = j >> 6;
    const float* row = predict + (size_t)pix * 19;
    float pv = conv_b[0];
    #pragma unroll
    for (int i = 0; i < 19; ++i) {
        float sg = __builtin_amdgcn_rcpf(1.0f + __builtin_exp2f(-1.442695041f * row[i]));
        pv += (1.0f - sg) * conv_w[i];
    }

    const int b = j >> 18, h = (j >> 12) & 63, d = (j >> 6) & 63, c = j & 63;
    const size_t pif = ((size_t)(b*64 + d) << 12) + h*64 + c;
    float sx = 0.f, sy = 0.f, sz = 0.f, sw = 0.f;
    for (int ks = 0; ks < nsplit; ++ks) {
        float4 pk = *(const float4*)&Pin[((size_t)ks << 20) + pif];
        sx += pk.x; sy += pk.y; sz += pk.z; sw += pk.w;
    }
    const float g = gate[0];
    float4 f = ((const float4*)feature)[i4];
    float4 x = ((const float4*)x1)[i4];
    float4 o;
    o.x = pv * (f.x + x.x + g * sx);
    o.y = pv * (f.y + x.y + g * sy);
    o.z = pv * (f.z + x.z + g * sz);
    o.w = pv * (f.w + x.w + g * sw);
    ((float4*)out)[i4] = o;
}

extern "C" void kernel_launch(void* const* d_in, const int* in_sizes, int n_in,
                              void* d_out, int out_size, void* d_ws, size_t ws_size,
                              hipStream_t stream) {
    const float* feature = (const float*)d_in[0];
    const float* predict = (const float*)d_in[1];
    const float* hq_w = (const float*)d_in[2];
    const float* hq_b = (const float*)d_in[3];
    const float* hv_w = (const float*)d_in[4];
    const float* hv_b = (const float*)d_in[5];
    const float* wq_w = (const float*)d_in[6];
    const float* wq_b = (const float*)d_in[7];
    const float* wv_w = (const float*)d_in[8];
    const float* wv_b = (const float*)d_in[9];
    const float* h_gate = (const float*)d_in[10];
    const float* w_gate = (const float*)d_in[11];
    const float* conv_w = (const float*)d_in[12];
    const float* conv_b = (const float*)d_in[13];
    float* out = (float*)d_out;

    // workspace: Qg 2MB | Vtg 2MB | x1 4MB | P nsplit*4MB (nsplit=4 -> 24 MiB)
    char* ws = (char*)d_ws;
    unsigned short* Qg  = (unsigned short*)(ws);
    unsigned short* Vtg = (unsigned short*)(ws + (2u << 20));
    float*          x1  = (float*)(ws + (4u << 20));
    float*          P   = (float*)(ws + (8u << 20));
    const int nsplit = 4;

    dim3 blk(256);
    // height stage
    prep_kernel<<<dim3(64, 4), blk, 0, stream>>>(feature, hq_w, hq_b, hv_w, hv_b,
                                                 Qg, Vtg);
    attn_kernel<<<dim3(32, 4, nsplit), blk, 0, stream>>>(Qg, Vtg, P);
    // width stage: x1 = feature + h_gate*sum(P) fused into staging
    prep_w_kernel<<<dim3(64, 4), blk, 0, stream>>>(feature, P, h_gate,
                                                   wq_w, wq_b, wv_w, wv_b,
                                                   Qg, Vtg, x1, nsplit);
    attn_kernel<<<dim3(32, 4, nsplit), blk, 0, stream>>>(Qg, Vtg, P);
    // out = p * (feature + x1 + w_gate*sum(P))
    final_kernel<<<dim3(1024), blk, 0, stream>>>(feature, x1, P, predict,
                                                 conv_w, conv_b, w_gate, out, nsplit);
}